// Round 16
// baseline (1466.004 us; speedup 1.0000x reference)
//
#include <hip/hip_runtime.h>
#include <hip/hip_cooperative_groups.h>
#include <hip/hip_bf16.h>

namespace cg = cooperative_groups;

// ---------------------------------------------------------------------------
// PatchGAT on MI355X. Round 16: ONE cooperative kernel, 14 phases separated by
// grid.sync(). R15 device code; launch grid now computed from the occupancy
// API (R15's hard-coded 1024 blocks exceeded co-residency -> launch rejected,
// output stayed zero). N=20000, E=320000, F_IN=HID=OUT=128, H=4, H*D=512.
// ---------------------------------------------------------------------------

typedef __attribute__((ext_vector_type(8))) short bf16x8;
typedef __attribute__((ext_vector_type(4))) float f32x4;
typedef __hip_bfloat16 bf16_t;

#define NEG_SLOPE 0.2f

__device__ __forceinline__ unsigned int pack_bf16(float lo, float hi) {
  return (((unsigned int)__bfloat16_as_ushort(__float2bfloat16(hi))) << 16) |
         (unsigned int)__bfloat16_as_ushort(__float2bfloat16(lo));
}

__device__ __forceinline__ float leaky_exp(float e) {
  e = (e > 0.f) ? e : NEG_SLOPE * e;
  return __expf(e);
}

// async 16B global->LDS DMA; LDS dest = wave-uniform base + lane*16
__device__ __forceinline__ void gld16(const void* g, void* l) {
  __builtin_amdgcn_global_load_lds(
      (const __attribute__((address_space(1))) void*)g,
      (__attribute__((address_space(3))) void*)l, 16, 0, 0);
}

// ---- 64x64 MFMA gemm tiles over fused [M,1024] output + el/er column
__device__ __forceinline__ void gemm_fused_phase(
    const bf16_t* __restrict__ A, const bf16_t* __restrict__ Bt,
    const float* __restrict__ ALRl, bf16_t* __restrict__ featB,
    bf16_t* __restrict__ resB, float* __restrict__ el, float* __restrict__ er,
    int M, int K, bf16_t* As, bf16_t* Bs, int tid, int bid, int nB) {
  int nRow = (M + 63) / 64;
  int tiles = 17 * nRow;
  int lane = tid & 63, wave = tid >> 6;
  int q = lane >> 4, r16 = lane & 15;
  int wm = (wave >> 1) * 32, wn = (wave & 1) * 32;
  for (int t = bid; t < tiles; t += nB) {
    int bx = t / nRow, by = t % nRow;
    int rowBase = by * 64;
    if (bx == 16) {  // el/er: 4 threads per row, 32 k each
      float* sALR = (float*)As;  // 4 KB
      for (int j = tid; j < 1024; j += 256) sALR[j] = ALRl[j];
      __syncthreads();
      int row = rowBase + (tid >> 2);
      int q4 = tid & 3;
      if (row < M) {
        const bf16_t* xr = A + (size_t)row * K + q4 * 32;
        float s[8] = {};
#pragma unroll
        for (int g = 0; g < 4; g++) {
          bf16x8 v = *(const bf16x8*)(xr + g * 8);
#pragma unroll
          for (int e = 0; e < 8; e++) {
            float f = __uint_as_float(((unsigned int)(unsigned short)v[e]) << 16);
            const float* Ak = sALR + (q4 * 32 + g * 8 + e) * 8;
#pragma unroll
            for (int cc = 0; cc < 8; cc++) s[cc] += f * Ak[cc];
          }
        }
#pragma unroll
        for (int cc = 0; cc < 8; cc++) {
          s[cc] += __shfl_xor(s[cc], 1);
          s[cc] += __shfl_xor(s[cc], 2);
        }
        if (q4 == 0)
          *(float4*)(el + row * 4) = make_float4(s[0], s[1], s[2], s[3]);
        else if (q4 == 1)
          *(float4*)(er + row * 4) = make_float4(s[4], s[5], s[6], s[7]);
      }
      __syncthreads();
      continue;
    }
    int colBase = bx * 64;
    bf16_t* Cb = (colBase < 512) ? featB : resB;
    int colOff = (colBase < 512) ? colBase : colBase - 512;
    f32x4 acc[2][2] = {};
    for (int k0 = 0; k0 < K; k0 += 64) {
#pragma unroll
      for (int p = 0; p < 2; p++) {
        int slotb = (wave * 2 + p) * 64;
        int s = slotb + lane;
        int r = s >> 3;
        int c = (s & 7) ^ (r & 7);
        int gr = rowBase + r;
        if (gr > M - 1) gr = M - 1;
        gld16(A + (size_t)gr * K + k0 + c * 8, (char*)As + (size_t)slotb * 16);
        gld16(Bt + (size_t)(colBase + r) * K + k0 + c * 8,
              (char*)Bs + (size_t)slotb * 16);
      }
      __syncthreads();
#pragma unroll
      for (int ks = 0; ks < 64; ks += 32) {
        int koff = ks >> 3;
        bf16x8 af[2], bfr[2];
#pragma unroll
        for (int i = 0; i < 2; i++) {
          int R = wm + i * 16 + r16;
          int slot = R * 8 + ((q + koff) ^ (R & 7));
          af[i] = *(const bf16x8*)((const char*)As + (size_t)slot * 16);
        }
#pragma unroll
        for (int j = 0; j < 2; j++) {
          int R = wn + j * 16 + r16;
          int slot = R * 8 + ((q + koff) ^ (R & 7));
          bfr[j] = *(const bf16x8*)((const char*)Bs + (size_t)slot * 16);
        }
#pragma unroll
        for (int i = 0; i < 2; i++)
#pragma unroll
          for (int j = 0; j < 2; j++)
            acc[i][j] = __builtin_amdgcn_mfma_f32_16x16x32_bf16(af[i], bfr[j], acc[i][j], 0, 0, 0);
      }
      __syncthreads();
    }
    int odd = lane & 1;
    int colb0 = r16 & ~1;
#pragma unroll
    for (int i = 0; i < 2; i++) {
#pragma unroll
      for (int rr = 0; rr < 4; rr++) {
        int row = rowBase + wm + i * 16 + q * 4 + rr;
        float a0 = acc[i][0][rr], a1 = acc[i][1][rr];
        float p0 = __shfl_xor(a0, 1), p1 = __shfl_xor(a1, 1);
        float lo = odd ? p1 : a0, hi = odd ? a1 : p0;
        int col = colOff + wn + odd * 16 + colb0;
        if (row < M)
          *(unsigned int*)(Cb + (size_t)row * 512 + col) = pack_bf16(lo, hi);
      }
    }
  }
}

// ---- 64x64 dense gemm phase (bias+relu), C[M,128]
__device__ __forceinline__ void dense_phase(
    const bf16_t* __restrict__ A, const bf16_t* __restrict__ Bt,
    const float* __restrict__ bias, bf16_t* __restrict__ C,
    int M, int K, bf16_t* As, bf16_t* Bs, int tid, int bid, int nB) {
  int nRow = (M + 63) / 64;
  int tiles = 2 * nRow;
  int lane = tid & 63, wave = tid >> 6;
  int q = lane >> 4, r16 = lane & 15;
  int wm = (wave >> 1) * 32, wn = (wave & 1) * 32;
  for (int t = bid; t < tiles; t += nB) {
    int bx = t / nRow, by = t % nRow;
    int rowBase = by * 64, colBase = bx * 64;
    f32x4 acc[2][2] = {};
    for (int k0 = 0; k0 < K; k0 += 64) {
#pragma unroll
      for (int p = 0; p < 2; p++) {
        int slotb = (wave * 2 + p) * 64;
        int s = slotb + lane;
        int r = s >> 3;
        int c = (s & 7) ^ (r & 7);
        int gr = rowBase + r;
        if (gr > M - 1) gr = M - 1;
        gld16(A + (size_t)gr * K + k0 + c * 8, (char*)As + (size_t)slotb * 16);
        gld16(Bt + (size_t)(colBase + r) * K + k0 + c * 8,
              (char*)Bs + (size_t)slotb * 16);
      }
      __syncthreads();
#pragma unroll
      for (int ks = 0; ks < 64; ks += 32) {
        int koff = ks >> 3;
        bf16x8 af[2], bfr[2];
#pragma unroll
        for (int i = 0; i < 2; i++) {
          int R = wm + i * 16 + r16;
          int slot = R * 8 + ((q + koff) ^ (R & 7));
          af[i] = *(const bf16x8*)((const char*)As + (size_t)slot * 16);
        }
#pragma unroll
        for (int j = 0; j < 2; j++) {
          int R = wn + j * 16 + r16;
          int slot = R * 8 + ((q + koff) ^ (R & 7));
          bfr[j] = *(const bf16x8*)((const char*)Bs + (size_t)slot * 16);
        }
#pragma unroll
        for (int i = 0; i < 2; i++)
#pragma unroll
          for (int j = 0; j < 2; j++)
            acc[i][j] = __builtin_amdgcn_mfma_f32_16x16x32_bf16(af[i], bfr[j], acc[i][j], 0, 0, 0);
      }
      __syncthreads();
    }
    int odd = lane & 1;
    int colb0 = r16 & ~1;
#pragma unroll
    for (int i = 0; i < 2; i++) {
#pragma unroll
      for (int rr = 0; rr < 4; rr++) {
        int row = rowBase + wm + i * 16 + q * 4 + rr;
        float a0 = acc[i][0][rr], a1 = acc[i][1][rr];
        float p0 = __shfl_xor(a0, 1), p1 = __shfl_xor(a1, 1);
        float lo = odd ? p1 : a0, hi = odd ? a1 : p0;
        int col = colBase + wn + odd * 16 + colb0;
        if (row < M) {
          float o0 = fmaxf(lo + bias[col], 0.f);
          float o1 = fmaxf(hi + bias[col + 1], 0.f);
          *(unsigned int*)(C + (size_t)row * 128 + col) = pack_bf16(o0, o1);
        }
      }
    }
  }
}

// ---- edge-weight phase (CSR order)
__device__ __forceinline__ void w_phase(
    const int* __restrict__ edge_src, const int* __restrict__ edge_dst,
    const float* __restrict__ el, const float* __restrict__ er,
    float* __restrict__ wcsr, int E, int tid, int bid, int nB) {
  for (int p = bid * 256 + tid; p < E; p += nB * 256) {
    int s = edge_src[p];
    int d = edge_dst[p];
    float4 elv = *(const float4*)(el + s * 4);
    float4 erv = *(const float4*)(er + d * 4);
    float4 w;
    w.x = leaky_exp(elv.x + erv.x);
    w.y = leaky_exp(elv.y + erv.y);
    w.z = leaky_exp(elv.z + erv.z);
    w.w = leaky_exp(elv.w + erv.w);
    *(float4*)(wcsr + (size_t)p * 4) = w;
  }
}

// ---- aggregation phase: block-per-node grid-strided (R12/R13 structure)
__device__ __forceinline__ void agg_phase(
    const bf16_t* __restrict__ featB, const bf16_t* __restrict__ resB,
    const float* __restrict__ wcsr, const float* __restrict__ bias,
    const int* __restrict__ row_ptr, const int* __restrict__ edge_src,
    bf16_t* __restrict__ out, float* __restrict__ partials, int N, int pool,
    bf16_t* As, bf16_t* Bs, int tid, int bid, int nB) {
  float(*accL)[64][8] = (float(*)[64][8])As;  // 8 KB
  float(*ssumL)[4] = (float(*)[4])Bs;         // 64 B
  float2* red = (float2*)((char*)Bs + 128);   // 2 KB
  int wave = tid >> 6, lane = tid & 63;
  int hh = lane >> 4;
  for (int n = bid; n < N; n += nB) {
    int start = row_ptr[n];
    int deg = row_ptr[n + 1] - start;
    float acc[8] = {};
    float ssum = 0.f;
    const bf16_t* fbase = featB + (size_t)lane * 8;
    for (int i = wave; i < deg; i += 4) {
      int p = start + i;
      int s = edge_src[p];
      float wv = wcsr[(size_t)p * 4 + hh];
      ssum += wv;
      uint4 f = *(const uint4*)(fbase + (size_t)s * 512);
      unsigned int u[4] = {f.x, f.y, f.z, f.w};
#pragma unroll
      for (int j = 0; j < 4; j++) {
        acc[2 * j] += wv * __uint_as_float(u[j] << 16);
        acc[2 * j + 1] += wv * __uint_as_float(u[j] & 0xffff0000u);
      }
    }
    *(float4*)&accL[wave][lane][0] = make_float4(acc[0], acc[1], acc[2], acc[3]);
    *(float4*)&accL[wave][lane][4] = make_float4(acc[4], acc[5], acc[6], acc[7]);
    if ((lane & 15) == 0) ssumL[wave][hh] = ssum;
    __syncthreads();
    int d = tid * 2;
    int l = d >> 3, j = d & 7;
    float a0 = 0.f, a1 = 0.f;
#pragma unroll
    for (int w = 0; w < 4; w++) {
      a0 += accL[w][l][j];
      a1 += accL[w][l][j + 1];
    }
    int h = tid >> 6;
    float ssum4 = ssumL[0][h] + ssumL[1][h] + ssumL[2][h] + ssumL[3][h];
    float inv = (deg > 0) ? 1.f / ssum4 : 0.f;
    unsigned int ru = *(const unsigned int*)(resB + (size_t)n * 512 + d);
    float2 bv = *(const float2*)(bias + d);
    float o0 = fmaxf(a0 * inv + __uint_as_float(ru << 16) + bv.x, 0.f);
    float o1 = fmaxf(a1 * inv + __uint_as_float(ru & 0xffff0000u) + bv.y, 0.f);
    if (!pool) {
      *(unsigned int*)(out + (size_t)n * 512 + d) = pack_bf16(o0, o1);
      __syncthreads();  // accL safe before next n
    } else {
      __syncthreads();
      red[tid] = make_float2(o0, o1);
      __syncthreads();
      if (tid < 64) {
        float m0 = 0.25f * (red[tid].x + red[tid + 64].x + red[tid + 128].x + red[tid + 192].x);
        float m1 = 0.25f * (red[tid].y + red[tid + 64].y + red[tid + 128].y + red[tid + 192].y);
        float* slot = partials + (n & 63) * 128;
        atomicMax((int*)slot + 2 * tid, __float_as_int(m0));
        atomicMax((int*)slot + 2 * tid + 1, __float_as_int(m1));
      }
      __syncthreads();
    }
  }
}

// ---------------------------------------------------------------------------
__global__ __launch_bounds__(256, 4) void fused_all(
    const float* n_feat, const int* src, const int* dst,
    const float* W0, const float* al0, const float* ar0, const float* b0,
    const float* rW0, const float* DW0, const float* Db0,
    const float* W1, const float* al1, const float* ar1, const float* b1,
    const float* rW1, const float* DW1, const float* Db1,
    const float* W2, const float* al2, const float* ar2, const float* b2,
    const float* rW2,
    bf16_t* xbf, bf16_t* featB, bf16_t* resB, bf16_t* outC, bf16_t* denseD,
    bf16_t* wts, float* ALR, float* el, float* er, float* partials,
    float* wcsr, int* counts, int* row_ptr, int* cursor,
    int* edge_src, int* edge_dst, float* d_out_f, int N, int E) {
  cg::grid_group grid = cg::this_grid();
  __shared__ bf16_t As[64 * 64];  // 8 KB
  __shared__ bf16_t Bs[64 * 64];  // 8 KB
  int tid = threadIdx.x;
  int bid = blockIdx.x;
  int nB = gridDim.x;

  bf16_t* FW0 = wts;
  bf16_t* FW1 = wts + 131072;
  bf16_t* FW2 = wts + 262144;
  bf16_t* DWt0 = wts + 393216;
  bf16_t* DWt1 = wts + 458752;

  // ---- phase 0: weight transposes + ALR + convert + zero counts/partials
  {
    float(*tile)[33] = (float(*)[33])As;  // 4224 B
    int r = tid >> 5, c = tid & 31;
    int convCnt = ((N * 128 / 4) + 255) / 256;
    int total = 524 + convCnt + 1;
    for (int b = bid; b < total; b += nB) {
      if (b < 384) {
        int mat = b >> 6, t = b & 63;
        int kt = t >> 4, nt = t & 15;
        int L = mat >> 1, isR = mat & 1;
        const float* S = (L == 0) ? (isR ? rW0 : W0)
                       : (L == 1) ? (isR ? rW1 : W1) : (isR ? rW2 : W2);
        bf16_t* D = wts + L * 131072 + isR * 65536;
#pragma unroll
        for (int rr = 0; rr < 4; rr++)
          tile[r + rr * 8][c] = S[(kt * 32 + r + rr * 8) * 512 + nt * 32 + c];
        __syncthreads();
#pragma unroll
        for (int rr = 0; rr < 4; rr++)
          D[(nt * 32 + r + rr * 8) * 128 + kt * 32 + c] =
              __float2bfloat16(tile[c][r + rr * 8]);
      } else if (b < 512) {
        int i = b - 384;
        int mat = i >> 6, t = i & 63;
        int kt = t & 15, nt = t >> 4;
        const float* S = mat ? DW1 : DW0;
        bf16_t* D = wts + 393216 + mat * 65536;
#pragma unroll
        for (int rr = 0; rr < 4; rr++)
          tile[r + rr * 8][c] = S[(kt * 32 + r + rr * 8) * 128 + nt * 32 + c];
        __syncthreads();
#pragma unroll
        for (int rr = 0; rr < 4; rr++)
          D[(nt * 32 + r + rr * 8) * 512 + kt * 32 + c] =
              __float2bfloat16(tile[c][r + rr * 8]);
      } else if (b < 524) {
        int idx = (b - 512) * 256 + tid;
        if (idx < 3072) {
          int L = idx >> 10;
          int k = (idx >> 3) & 127;
          int cc = idx & 7;
          int h = cc & 3;
          const float* W = (L == 0) ? W0 : (L == 1) ? W1 : W2;
          const float* a = (cc < 4) ? ((L == 0) ? al0 : (L == 1) ? al1 : al2)
                                    : ((L == 0) ? ar0 : (L == 1) ? ar1 : ar2);
          float s = 0.f;
          for (int d = 0; d < 128; d++)
            s += W[k * 512 + h * 128 + d] * a[h * 128 + d];
          ALR[idx] = s;
        }
      } else if (b < 524 + convCnt) {
        int i = ((b - 524) * 256 + tid) * 4;
        if (i < N * 128) {
          float4 v = *(const float4*)(n_feat + i);
          xbf[i + 0] = __float2bfloat16(v.x);
          xbf[i + 1] = __float2bfloat16(v.y);
          xbf[i + 2] = __float2bfloat16(v.z);
          xbf[i + 3] = __float2bfloat16(v.w);
        }
      } else {
        for (int i = tid; i < N; i += 256) counts[i] = 0;
        for (int i = tid; i < 64 * 128; i += 256) partials[i] = 0.f;
      }
      __syncthreads();
    }
  }
  grid.sync();

  // ---- phase 1: L0 GEMM (+el/er) then degree count
  gemm_fused_phase(xbf, FW0, ALR, featB, resB, el, er, N, 128, As, Bs, tid, bid, nB);
  for (int i = bid * 256 + tid; i < E; i += nB * 256) atomicAdd(&counts[dst[i]], 1);
  grid.sync();

  // ---- phase 2: CSR scan (block 0)
  if (bid == 0) {
    int* sums = (int*)As;  // 1 KB
    int chunk = (N + 255) / 256;
    int begin = tid * chunk;
    int end = begin + chunk;
    if (end > N) end = N;
    int s = 0;
    for (int i = begin; i < end; i++) s += counts[i];
    sums[tid] = s;
    __syncthreads();
    for (int off = 1; off < 256; off <<= 1) {
      int v = (tid >= off) ? sums[tid - off] : 0;
      __syncthreads();
      sums[tid] += v;
      __syncthreads();
    }
    int run = (tid == 0) ? 0 : sums[tid - 1];
    for (int i = begin; i < end; i++) {
      row_ptr[i] = run;
      cursor[i] = run;
      run += counts[i];
    }
    if (tid == 255) row_ptr[N] = sums[255];
  }
  grid.sync();

  // ---- phase 3: scatter + L0 edge weights
  for (int i = bid * 256 + tid; i < E; i += nB * 256) {
    int s = src[i];
    int d = dst[i];
    int pos = atomicAdd(&cursor[d], 1);
    edge_src[pos] = s;
    edge_dst[pos] = d;
    float4 elv = *(const float4*)(el + s * 4);
    float4 erv = *(const float4*)(er + d * 4);
    float4 w;
    w.x = leaky_exp(elv.x + erv.x);
    w.y = leaky_exp(elv.y + erv.y);
    w.z = leaky_exp(elv.z + erv.z);
    w.w = leaky_exp(elv.w + erv.w);
    *(float4*)(wcsr + (size_t)pos * 4) = w;
  }
  grid.sync();

  // ---- phase 4: agg L0
  agg_phase(featB, resB, wcsr, b0, row_ptr, edge_src, outC, partials, N, 0,
            As, Bs, tid, bid, nB);
  grid.sync();
  // ---- phase 5: dense L0
  dense_phase(outC, DWt0, Db0, denseD, N, 512, As, Bs, tid, bid, nB);
  grid.sync();
  // ---- phase 6: L1 GEMM (+el/er)
  gemm_fused_phase(denseD, FW1, ALR + 1024, featB, resB, el, er, N, 128, As, Bs, tid, bid, nB);
  grid.sync();
  // ---- phase 7: L1 weights
  w_phase(edge_src, edge_dst, el, er, wcsr, E, tid, bid, nB);
  grid.sync();
  // ---- phase 8: agg L1
  agg_phase(featB, resB, wcsr, b1, row_ptr, edge_src, outC, partials, N, 0,
            As, Bs, tid, bid, nB);
  grid.sync();
  // ---- phase 9: dense L1
  dense_phase(outC, DWt1, Db1, denseD, N, 512, As, Bs, tid, bid, nB);
  grid.sync();
  // ---- phase 10: L2 GEMM (+el/er)
  gemm_fused_phase(denseD, FW2, ALR + 2048, featB, resB, el, er, N, 128, As, Bs, tid, bid, nB);
  grid.sync();
  // ---- phase 11: L2 weights
  w_phase(edge_src, edge_dst, el, er, wcsr, E, tid, bid, nB);
  grid.sync();
  // ---- phase 12: agg L2 + pool partials
  agg_phase(featB, resB, wcsr, b2, row_ptr, edge_src, outC, partials, N, 1,
            As, Bs, tid, bid, nB);
  grid.sync();
  // ---- phase 13: finish pool (block 0)
  if (bid == 0 && tid < 128) {
    float m = 0.f;
    for (int s = 0; s < 64; s++) m = fmaxf(m, partials[s * 128 + tid]);
    d_out_f[tid] = m;
  }
}

// ---------------------------------------------------------------------------
extern "C" void kernel_launch(void* const* d_in, const int* in_sizes, int n_in,
                              void* d_out, int out_size, void* d_ws, size_t ws_size,
                              hipStream_t stream) {
  const float* n_feat = (const float*)d_in[0];
  const int* src = (const int*)d_in[1];
  const int* dst = (const int*)d_in[2];
  const float* W0 = (const float*)d_in[3];
  const float* al0 = (const float*)d_in[4];
  const float* ar0 = (const float*)d_in[5];
  const float* b0 = (const float*)d_in[6];
  const float* rW0 = (const float*)d_in[7];
  const float* DW0 = (const float*)d_in[8];
  const float* Db0 = (const float*)d_in[9];
  const float* W1 = (const float*)d_in[10];
  const float* al1 = (const float*)d_in[11];
  const float* ar1 = (const float*)d_in[12];
  const float* b1 = (const float*)d_in[13];
  const float* rW1 = (const float*)d_in[14];
  const float* DW1 = (const float*)d_in[15];
  const float* Db1 = (const float*)d_in[16];
  const float* W2 = (const float*)d_in[17];
  const float* al2 = (const float*)d_in[18];
  const float* ar2 = (const float*)d_in[19];
  const float* b2 = (const float*)d_in[20];
  const float* rW2 = (const float*)d_in[21];

  int N = in_sizes[0] / 128;
  int E = in_sizes[1];

  bf16_t* xbf = (bf16_t*)d_ws;                        // [N,128]
  bf16_t* featB = xbf + (size_t)N * 128;              // [N,512]
  bf16_t* resB = featB + (size_t)N * 512;             // [N,512]
  bf16_t* outC = resB + (size_t)N * 512;              // [N,512]
  bf16_t* denseD = outC + (size_t)N * 512;            // [N,128]
  bf16_t* wts = denseD + (size_t)N * 128;             // 524288
  float* ALR = (float*)(wts + 524288);                // [3][128][8]
  float* el = ALR + 3072;                             // [N,4]
  float* er = el + (size_t)N * 4;                     // [N,4]
  float* partials = er + (size_t)N * 4;               // [64][128]
  float* wcsr = partials + 64 * 128;                  // [E,4]
  int* counts = (int*)(wcsr + (size_t)E * 4);         // [N]
  int* row_ptr = counts + N;                          // [N+1]
  int* cursor = row_ptr + (N + 1);                    // [N]
  int* edge_src = cursor + N;                         // [E]
  int* edge_dst = edge_src + E;                       // [E]
  float* d_out_f = (float*)d_out;

  void* args[] = {
      (void*)&n_feat, (void*)&src, (void*)&dst,
      (void*)&W0, (void*)&al0, (void*)&ar0, (void*)&b0, (void*)&rW0,
      (void*)&DW0, (void*)&Db0,
      (void*)&W1, (void*)&al1, (void*)&ar1, (void*)&b1, (void*)&rW1,
      (void*)&DW1, (void*)&Db1,
      (void*)&W2, (void*)&al2, (void*)&ar2, (void*)&b2, (void*)&rW2,
      (void*)&xbf, (void*)&featB, (void*)&resB, (void*)&outC, (void*)&denseD,
      (void*)&wts, (void*)&ALR, (void*)&el, (void*)&er, (void*)&partials,
      (void*)&wcsr, (void*)&counts, (void*)&row_ptr, (void*)&cursor,
      (void*)&edge_src, (void*)&edge_dst, (void*)&d_out_f, (void*)&N, (void*)&E};

  // Legal cooperative grid = occupancy-per-CU x numCUs (R15 hard-coded 1024
  // and the driver rejected the launch -> kernel never ran).
  int blocksPerCU = 0;
  hipOccupancyMaxActiveBlocksPerMultiprocessor(&blocksPerCU, fused_all, 256, 0);
  if (blocksPerCU < 1) blocksPerCU = 1;
  hipDeviceProp_t prop;
  int dev = 0;
  hipGetDevice(&dev);
  hipGetDeviceProperties(&prop, dev);
  int grid = blocksPerCU * prop.multiProcessorCount;
  if (grid < 64) grid = 64;

  hipLaunchCooperativeKernel((const void*)fused_all, dim3(grid), dim3(256),
                             args, 0, stream);
}

// Round 17
// 413.290 us; speedup vs baseline: 3.5472x; 3.5472x over previous
//
#include <hip/hip_runtime.h>
#include <hip/hip_bf16.h>

// ---------------------------------------------------------------------------
// PatchGAT on MI355X. Round 17: restore R12 (verified 413.7 us optimum).
// Cooperative mega-kernel falsified in R16: grid.sync() ~100us each on 8-XCD
// MI355X >> graph-replay dispatch boundary (~3-10us). 12 dispatches.
// N=20000, E=320000, F_IN=HID=OUT=128, H=4, H*D=512.
// ---------------------------------------------------------------------------

typedef __attribute__((ext_vector_type(8))) short bf16x8;
typedef __attribute__((ext_vector_type(4))) float f32x4;
typedef __hip_bfloat16 bf16_t;

__device__ __forceinline__ unsigned int pack_bf16(float lo, float hi) {
  return (((unsigned int)__bfloat16_as_ushort(__float2bfloat16(hi))) << 16) |
         (unsigned int)__bfloat16_as_ushort(__float2bfloat16(lo));
}

// async 16B global->LDS DMA; LDS dest = wave-uniform base + lane*16
__device__ __forceinline__ void gload_lds16(const void* g, void* l) {
  __builtin_amdgcn_global_load_lds(
      (const __attribute__((address_space(1))) void*)g,
      (__attribute__((address_space(3))) void*)l, 16, 0, 0);
}

// ---------------- mega-prep: ONE launch does
//  blocks [0,384):    6x [128,512]->[512,128] transposes (W,rW per layer)
//  blocks [384,512):  2x [512,128]->[128,512] transposes (DW0,DW1)
//  blocks [512,524):  ALR[L][k][c] = sum_d W_L[k,h*128+d]*(al|ar)_L[h,d]
//  blocks [524,3024): n_feat fp32 -> bf16
//  block  3024:       zero counts[N] and pool partials [64][128]
__global__ __launch_bounds__(256) void mega_prep(
    const float* __restrict__ W0, const float* __restrict__ rW0,
    const float* __restrict__ W1, const float* __restrict__ rW1,
    const float* __restrict__ W2, const float* __restrict__ rW2,
    const float* __restrict__ DW0, const float* __restrict__ DW1,
    const float* __restrict__ al0, const float* __restrict__ ar0,
    const float* __restrict__ al1, const float* __restrict__ ar1,
    const float* __restrict__ al2, const float* __restrict__ ar2,
    const float* __restrict__ n_feat, bf16_t* __restrict__ wts,
    float* __restrict__ ALR, bf16_t* __restrict__ xbf,
    int* __restrict__ counts, float* __restrict__ partials, int N) {
  __shared__ float tile[32][33];
  int b = blockIdx.x, tid = threadIdx.x;
  int r = tid >> 5, c = tid & 31;

  if (b < 384) {  // W/rW transposes: [128,512] -> [512,128]; 6 mats x 64 tiles
    int mat = b >> 6;            // 0..5: L*2 + isR
    int t = b & 63;
    int kt = t >> 4, nt = t & 15;
    int L = mat >> 1, isR = mat & 1;
    const float* S = (L == 0) ? (isR ? rW0 : W0)
                   : (L == 1) ? (isR ? rW1 : W1) : (isR ? rW2 : W2);
    bf16_t* D = wts + L * 131072 + isR * 65536;  // [512 rows,128 cols]
#pragma unroll
    for (int rr = 0; rr < 4; rr++)
      tile[r + rr * 8][c] = S[(kt * 32 + r + rr * 8) * 512 + nt * 32 + c];
    __syncthreads();
#pragma unroll
    for (int rr = 0; rr < 4; rr++)
      D[(nt * 32 + r + rr * 8) * 128 + kt * 32 + c] =
          __float2bfloat16(tile[c][r + rr * 8]);
  } else if (b < 512) {  // DW transposes: [512,128] -> [128,512]; 2 mats x 64
    int i = b - 384;
    int mat = i >> 6;
    int t = i & 63;
    int kt = t & 15, nt = t >> 4;  // k: 16 tiles, n: 4 tiles
    const float* S = mat ? DW1 : DW0;
    bf16_t* D = wts + 393216 + mat * 65536;  // [128 rows,512 cols]
#pragma unroll
    for (int rr = 0; rr < 4; rr++)
      tile[r + rr * 8][c] = S[(kt * 32 + r + rr * 8) * 128 + nt * 32 + c];
    __syncthreads();
#pragma unroll
    for (int rr = 0; rr < 4; rr++)
      D[(nt * 32 + r + rr * 8) * 512 + kt * 32 + c] =
          __float2bfloat16(tile[c][r + rr * 8]);
  } else if (b < 524) {  // ALR
    int idx = (b - 512) * 256 + tid;
    if (idx < 3072) {
      int L = idx >> 10;
      int k = (idx >> 3) & 127;
      int cc = idx & 7;
      int h = cc & 3;
      const float* W = (L == 0) ? W0 : (L == 1) ? W1 : W2;
      const float* a = (cc < 4) ? ((L == 0) ? al0 : (L == 1) ? al1 : al2)
                                : ((L == 0) ? ar0 : (L == 1) ? ar1 : ar2);
      float s = 0.f;
      for (int d = 0; d < 128; d++) s += W[k * 512 + h * 128 + d] * a[h * 128 + d];
      ALR[idx] = s;
    }
  } else if (b < 3024) {  // convert n_feat
    int i = ((b - 524) * 256 + tid) * 4;
    if (i < N * 128) {
      float4 v = *(const float4*)(n_feat + i);
      xbf[i + 0] = __float2bfloat16(v.x);
      xbf[i + 1] = __float2bfloat16(v.y);
      xbf[i + 2] = __float2bfloat16(v.z);
      xbf[i + 3] = __float2bfloat16(v.w);
    }
  } else {  // zero counts + pool partials
    for (int i = tid; i < N; i += 256) counts[i] = 0;
    for (int i = tid; i < 64 * 128; i += 256) partials[i] = 0.f;
  }
}

// ---------------- 128x128-tile MFMA GEMM + fused el/er column (+opt count).
// blockIdx.x < 8 : C[M,1024] tile = A[M,128] @ Bt[1024,128]^T (DMA-staged)
// blockIdx.x == 8: el/er[rowtile] = A[rowtile,128] @ ALR[128,8]
// blockIdx.x == 9 (COUNT only): CSR degree count (grid-stride over E)
template <bool COUNT>
__global__ __launch_bounds__(256) void gemm128el(
    const bf16_t* __restrict__ A, const bf16_t* __restrict__ Bt,
    const float* __restrict__ ALRl, bf16_t* __restrict__ C,
    float* __restrict__ el, float* __restrict__ er, int M, int ldc, int K,
    const int* __restrict__ dst, int* __restrict__ counts, int E) {
  __shared__ bf16_t As[128 * 64];  // 16 KB, XOR-swizzled
  __shared__ bf16_t Bs[128 * 64];
  int tid = threadIdx.x;
  int rowBase = blockIdx.y * 128;

  if (COUNT && blockIdx.x == 9) {
    int stride = gridDim.y * 256;
    for (int i = blockIdx.y * 256 + tid; i < E; i += stride)
      atomicAdd(&counts[dst[i]], 1);
    return;
  }

  if (blockIdx.x == 8) {
    // ---- el/er tile: 2 threads per row, 64 k each
    float* sALR = (float*)As;  // [128][8] fp32 = 4 KB
#pragma unroll
    for (int j = 0; j < 4; j++) sALR[tid * 4 + j] = ALRl[tid * 4 + j];
    __syncthreads();
    int row = rowBase + (tid >> 1);
    int half = tid & 1;
    if (row < M) {
      const bf16_t* xr = A + (size_t)row * K + half * 64;
      float s[8] = {};
#pragma unroll
      for (int g = 0; g < 8; g++) {
        bf16x8 v = *(const bf16x8*)(xr + g * 8);
#pragma unroll
        for (int e = 0; e < 8; e++) {
          float f = __uint_as_float(((unsigned int)(unsigned short)v[e]) << 16);
          const float* Ak = sALR + (half * 64 + g * 8 + e) * 8;
#pragma unroll
          for (int cc = 0; cc < 8; cc++) s[cc] += f * Ak[cc];
        }
      }
#pragma unroll
      for (int cc = 0; cc < 8; cc++) s[cc] += __shfl_xor(s[cc], 1);
      if (half == 0)
        *(float4*)(el + row * 4) = make_float4(s[0], s[1], s[2], s[3]);
      else
        *(float4*)(er + row * 4) = make_float4(s[4], s[5], s[6], s[7]);
    }
    return;
  }

  int lane = tid & 63, wave = tid >> 6;
  int q = lane >> 4, r16 = lane & 15;
  int wm = (wave >> 1) * 64, wn = (wave & 1) * 64;
  int colBase = blockIdx.x * 128;

  f32x4 acc[4][4] = {};

  for (int k0 = 0; k0 < K; k0 += 64) {
#pragma unroll
    for (int p = 0; p < 4; p++) {
      int slotb = (wave * 4 + p) * 64;  // wave-uniform LDS granule base
      int s = slotb + lane;
      int r = s >> 3;
      int c = (s & 7) ^ (r & 7);  // inverse swizzle on global side
      int gr = rowBase + r;
      if (gr > M - 1) gr = M - 1;  // clamp: dup rows, outputs masked
      gload_lds16(A + (size_t)gr * K + k0 + c * 8, (char*)As + (size_t)slotb * 16);
      gload_lds16(Bt + (size_t)(colBase + r) * K + k0 + c * 8,
                  (char*)Bs + (size_t)slotb * 16);
    }
    __syncthreads();
#pragma unroll
    for (int ks = 0; ks < 64; ks += 32) {
      int koff = ks >> 3;
      bf16x8 af[4], bfr[4];
#pragma unroll
      for (int i = 0; i < 4; i++) {
        int R = wm + i * 16 + r16;
        int slot = R * 8 + ((q + koff) ^ (R & 7));
        af[i] = *(const bf16x8*)((const char*)As + (size_t)slot * 16);
      }
#pragma unroll
      for (int j = 0; j < 4; j++) {
        int R = wn + j * 16 + r16;
        int slot = R * 8 + ((q + koff) ^ (R & 7));
        bfr[j] = *(const bf16x8*)((const char*)Bs + (size_t)slot * 16);
      }
#pragma unroll
      for (int i = 0; i < 4; i++)
#pragma unroll
        for (int j = 0; j < 4; j++)
          acc[i][j] = __builtin_amdgcn_mfma_f32_16x16x32_bf16(af[i], bfr[j], acc[i][j], 0, 0, 0);
    }
    __syncthreads();
  }

  int odd = lane & 1;
  int colb0 = r16 & ~1;
#pragma unroll
  for (int i = 0; i < 4; i++) {
#pragma unroll
    for (int r = 0; r < 4; r++) {
      int row = rowBase + wm + i * 16 + q * 4 + r;
#pragma unroll
      for (int jp = 0; jp < 2; jp++) {
        float a0 = acc[i][2 * jp][r];
        float a1 = acc[i][2 * jp + 1][r];
        float p0 = __shfl_xor(a0, 1);
        float p1 = __shfl_xor(a1, 1);
        float lo = odd ? p1 : a0;
        float hi = odd ? a1 : p0;
        int col = colBase + wn + (2 * jp + odd) * 16 + colb0;
        if (row < M)
          *(unsigned int*)(C + (size_t)row * ldc + col) = pack_bf16(lo, hi);
      }
    }
  }
}

// ---------------- 64x64-tile MFMA GEMM, BK=64, DMA-staged, bias+relu (dense)
__global__ __launch_bounds__(256) void mfma_gemm64(
    const bf16_t* __restrict__ A, const bf16_t* __restrict__ Bt,
    const float* __restrict__ bias, bf16_t* __restrict__ C,
    int M, int ldc, int K) {
  __shared__ bf16_t As[64 * 64];
  __shared__ bf16_t Bs[64 * 64];
  int tid = threadIdx.x;
  int lane = tid & 63, wave = tid >> 6;
  int q = lane >> 4, r16 = lane & 15;
  int wm = (wave >> 1) * 32, wn = (wave & 1) * 32;
  int rowBase = blockIdx.y * 64, colBase = blockIdx.x * 64;

  f32x4 acc[2][2] = {};

  for (int k0 = 0; k0 < K; k0 += 64) {
#pragma unroll
    for (int p = 0; p < 2; p++) {
      int slotb = (wave * 2 + p) * 64;
      int s = slotb + lane;
      int r = s >> 3;
      int c = (s & 7) ^ (r & 7);
      int gr = rowBase + r;
      if (gr > M - 1) gr = M - 1;
      gload_lds16(A + (size_t)gr * K + k0 + c * 8, (char*)As + (size_t)slotb * 16);
      gload_lds16(Bt + (size_t)(colBase + r) * K + k0 + c * 8,
                  (char*)Bs + (size_t)slotb * 16);
    }
    __syncthreads();
#pragma unroll
    for (int ks = 0; ks < 64; ks += 32) {
      int koff = ks >> 3;
      bf16x8 af[2], bfr[2];
#pragma unroll
      for (int i = 0; i < 2; i++) {
        int R = wm + i * 16 + r16;
        int slot = R * 8 + ((q + koff) ^ (R & 7));
        af[i] = *(const bf16x8*)((const char*)As + (size_t)slot * 16);
      }
#pragma unroll
      for (int j = 0; j < 2; j++) {
        int R = wn + j * 16 + r16;
        int slot = R * 8 + ((q + koff) ^ (R & 7));
        bfr[j] = *(const bf16x8*)((const char*)Bs + (size_t)slot * 16);
      }
#pragma unroll
      for (int i = 0; i < 2; i++)
#pragma unroll
        for (int j = 0; j < 2; j++)
          acc[i][j] = __builtin_amdgcn_mfma_f32_16x16x32_bf16(af[i], bfr[j], acc[i][j], 0, 0, 0);
    }
    __syncthreads();
  }

  int odd = lane & 1;
  int colb0 = r16 & ~1;
#pragma unroll
  for (int i = 0; i < 2; i++) {
#pragma unroll
    for (int r = 0; r < 4; r++) {
      int row = rowBase + wm + i * 16 + q * 4 + r;
      float a0 = acc[i][0][r];
      float a1 = acc[i][1][r];
      float p0 = __shfl_xor(a0, 1);
      float p1 = __shfl_xor(a1, 1);
      float lo = odd ? p1 : a0;
      float hi = odd ? a1 : p0;
      int col = colBase + wn + odd * 16 + colb0;
      if (row < M) {
        float o0 = fmaxf(lo + bias[col], 0.f);
        float o1 = fmaxf(hi + bias[col + 1], 0.f);
        *(unsigned int*)(C + (size_t)row * ldc + col) = pack_bf16(o0, o1);
      }
    }
  }
}

// ---------------- CSR scan + scatter
__global__ __launch_bounds__(1024) void scan_kernel(const int* __restrict__ counts,
                                                    int* __restrict__ row_ptr,
                                                    int* __restrict__ cursor, int N) {
  __shared__ int sums[1024];
  int t = threadIdx.x;
  int chunk = (N + 1023) / 1024;
  int begin = t * chunk;
  int end = begin + chunk;
  if (end > N) end = N;
  int s = 0;
  for (int i = begin; i < end; i++) s += counts[i];
  sums[t] = s;
  __syncthreads();
  for (int off = 1; off < 1024; off <<= 1) {
    int v = (t >= off) ? sums[t - off] : 0;
    __syncthreads();
    sums[t] += v;
    __syncthreads();
  }
  int run = (t == 0) ? 0 : sums[t - 1];
  for (int i = begin; i < end; i++) {
    row_ptr[i] = run;
    cursor[i] = run;
    run += counts[i];
  }
  if (t == 1023) row_ptr[N] = sums[1023];
}

__global__ __launch_bounds__(256) void scatter_kernel(
    const int* __restrict__ src, const int* __restrict__ dst,
    int* __restrict__ cursor, int* __restrict__ edge_src, int E) {
  int i = blockIdx.x * blockDim.x + threadIdx.x;
  if (i < E) {
    int d = dst[i];
    int pos = atomicAdd(&cursor[d], 1);
    edge_src[pos] = src[i];
  }
}

// ---------------- GAT aggregation (R9 optimum): block = node; wave covers the
// whole 512-dim row (all heads) of one edge per iteration; 4 waves stride
// edges by 4; LDS cross-wave reduction + fused epilogue.
// POOL: layer 2 — skip outC write, head-mean+relu, atomicMax into slot
// partials[64][128] (slot = n & 63, values nonneg, partials zeroed).
template <bool POOL>
__global__ __launch_bounds__(256) void gat_agg_kernel(
    const bf16_t* __restrict__ fused,  // [N,1024]: cols 0-511 feat, 512-1023 res
    const float* __restrict__ el, const float* __restrict__ er,
    const float* __restrict__ bias, const int* __restrict__ row_ptr,
    const int* __restrict__ edge_src, bf16_t* __restrict__ out,
    float* __restrict__ partials, int N) {
  __shared__ float accL[4][64][8];  // 8 KB
  __shared__ float ssumL[4][4];
  int n = blockIdx.x;
  int tid = threadIdx.x;
  int wave = tid >> 6, lane = tid & 63;
  int hh = lane >> 4;                    // head owned by this lane's dims
  int start = row_ptr[n];
  int deg = row_ptr[n + 1] - start;
  float er_h = er[n * 4 + hh];

  float acc[8] = {};
  float ssum = 0.f;
  const bf16_t* fbase = fused + (size_t)lane * 8;
  for (int i = wave; i < deg; i += 4) {
    int s = edge_src[start + i];
    float e = el[s * 4 + hh] + er_h;     // 16B line broadcast per 16 lanes
    e = (e > 0.f) ? e : 0.2f * e;
    float w = __expf(e);
    ssum += w;
    uint4 f = *(const uint4*)(fbase + (size_t)s * 1024);  // 8 dims, this head
    unsigned int u[4] = {f.x, f.y, f.z, f.w};
#pragma unroll
    for (int j = 0; j < 4; j++) {
      acc[2 * j] += w * __uint_as_float(u[j] << 16);
      acc[2 * j + 1] += w * __uint_as_float(u[j] & 0xffff0000u);
    }
  }
  *(float4*)&accL[wave][lane][0] = make_float4(acc[0], acc[1], acc[2], acc[3]);
  *(float4*)&accL[wave][lane][4] = make_float4(acc[4], acc[5], acc[6], acc[7]);
  if ((lane & 15) == 0) ssumL[wave][hh] = ssum;
  __syncthreads();

  // finalize: thread covers dims d, d+1 (d = tid*2)
  int d = tid * 2;
  int l = d >> 3, j = d & 7;
  float a0 = 0.f, a1 = 0.f;
#pragma unroll
  for (int w = 0; w < 4; w++) {
    a0 += accL[w][l][j];
    a1 += accL[w][l][j + 1];
  }
  int h = tid >> 6;
  float ssum4 = ssumL[0][h] + ssumL[1][h] + ssumL[2][h] + ssumL[3][h];
  float inv = (deg > 0) ? 1.f / ssum4 : 0.f;
  unsigned int ru = *(const unsigned int*)(fused + (size_t)n * 1024 + 512 + d);
  float2 bv = *(const float2*)(bias + d);
  float o0 = fmaxf(a0 * inv + __uint_as_float(ru << 16) + bv.x, 0.f);
  float o1 = fmaxf(a1 * inv + __uint_as_float(ru & 0xffff0000u) + bv.y, 0.f);

  if (!POOL) {
    *(unsigned int*)(out + (size_t)n * 512 + d) = pack_bf16(o0, o1);
  } else {
    // head-mean -> relu(=identity, nonneg) -> slot max
    float2* red = (float2*)accL;  // reuse (2 KB)
    __syncthreads();              // all accL reads above must complete
    red[tid] = make_float2(o0, o1);
    __syncthreads();
    if (tid < 64) {
      float m0 = 0.25f * (red[tid].x + red[tid + 64].x + red[tid + 128].x + red[tid + 192].x);
      float m1 = 0.25f * (red[tid].y + red[tid + 64].y + red[tid + 128].y + red[tid + 192].y);
      float* slot = partials + (n & 63) * 128;
      atomicMax((int*)slot + 2 * tid, __float_as_int(m0));
      atomicMax((int*)slot + 2 * tid + 1, __float_as_int(m1));
    }
  }
}

// ---------------- final: max over the 64 slot partials -> d_out[128]
__global__ __launch_bounds__(128) void pool_finish(const float* __restrict__ partials,
                                                   float* __restrict__ out) {
  int d = threadIdx.x;
  float m = 0.f;
#pragma unroll 8
  for (int s = 0; s < 64; s++) m = fmaxf(m, partials[s * 128 + d]);
  out[d] = m;
}

// ---------------------------------------------------------------------------
extern "C" void kernel_launch(void* const* d_in, const int* in_sizes, int n_in,
                              void* d_out, int out_size, void* d_ws, size_t ws_size,
                              hipStream_t stream) {
  const float* n_feat = (const float*)d_in[0];
  const int* src = (const int*)d_in[1];
  const int* dst = (const int*)d_in[2];
  const float* W0 = (const float*)d_in[3];
  const float* al0 = (const float*)d_in[4];
  const float* ar0 = (const float*)d_in[5];
  const float* b0 = (const float*)d_in[6];
  const float* rW0 = (const float*)d_in[7];
  const float* DW0 = (const float*)d_in[8];
  const float* Db0 = (const float*)d_in[9];
  const float* W1 = (const float*)d_in[10];
  const float* al1 = (const float*)d_in[11];
  const float* ar1 = (const float*)d_in[12];
  const float* b1 = (const float*)d_in[13];
  const float* rW1 = (const float*)d_in[14];
  const float* DW1 = (const float*)d_in[15];
  const float* Db1 = (const float*)d_in[16];
  const float* W2 = (const float*)d_in[17];
  const float* al2 = (const float*)d_in[18];
  const float* ar2 = (const float*)d_in[19];
  const float* b2 = (const float*)d_in[20];
  const float* rW2 = (const float*)d_in[21];

  const int N = in_sizes[0] / 128;
  const int E = in_sizes[1];

  // ---- workspace carve-up (16B-aligned throughout)
  bf16_t* xbf = (bf16_t*)d_ws;                        // [N,128]
  bf16_t* fusedFR = xbf + (size_t)N * 128;            // [N,1024] feat||res
  bf16_t* outC = fusedFR + (size_t)N * 1024;          // [N,512]
  bf16_t* denseD = outC + (size_t)N * 512;            // [N,128]
  bf16_t* wts = denseD + (size_t)N * 128;             // 524288
  float* ALR = (float*)(wts + 524288);                // [3][128][8]
  float* el = ALR + 3072;                             // [N,4]
  float* er = el + (size_t)N * 4;                     // [N,4]
  float* partials = er + (size_t)N * 4;               // [64][128]
  int* counts = (int*)(partials + 64 * 128);          // [N]
  int* row_ptr = counts + N;                          // [N+1]
  int* cursor = row_ptr + (N + 1);                    // [N]
  int* edge_src = cursor + N;                         // [E]

  bf16_t* FW0 = wts;                // [1024,128]
  bf16_t* FW1 = wts + 131072;
  bf16_t* FW2 = wts + 262144;
  bf16_t* DWt0 = wts + 393216;      // [128,512]
  bf16_t* DWt1 = wts + 458752;

  // ---- 1: weights transpose + ALR + convert + zero counts/partials
  mega_prep<<<3025, 256, 0, stream>>>(
      W0, rW0, W1, rW1, W2, rW2, DW0, DW1,
      al0, ar0, al1, ar1, al2, ar2,
      n_feat, wts, ALR, xbf, counts, partials, N);

  int nRow = (N + 127) / 128;       // 157
  dim3 gF0(10, nRow);               // 8 col-tiles + el/er + count
  dim3 gF(9, nRow);                 // 8 col-tiles + el/er
  dim3 gD(2, (N + 63) / 64);        // dense: 128 cols, 64-tile

  // ---- 2: layer-0 GEMM + el/er + CSR count (independent work, one launch)
  gemm128el<true><<<gF0, 256, 0, stream>>>(xbf, FW0, ALR, fusedFR, el, er,
                                           N, 1024, 128, dst, counts, E);
  // ---- 3,4: CSR scan + scatter
  scan_kernel<<<1, 1024, 0, stream>>>(counts, row_ptr, cursor, N);
  scatter_kernel<<<(E + 255) / 256, 256, 0, stream>>>(src, dst, cursor, edge_src, E);

  // ---- 5-7: layer 0 agg + dense; layer 1 GEMM
  gat_agg_kernel<false><<<N, 256, 0, stream>>>(fusedFR, el, er, b0, row_ptr,
                                               edge_src, outC, nullptr, N);
  mfma_gemm64<<<gD, 256, 0, stream>>>(outC, DWt0, Db0, denseD, N, 128, 512);
  gemm128el<false><<<gF, 256, 0, stream>>>(denseD, FW1, ALR + 1024, fusedFR,
                                           el, er, N, 1024, 128, nullptr, nullptr, 0);
  // ---- 8-10: layer 1 agg + dense; layer 2 GEMM
  gat_agg_kernel<false><<<N, 256, 0, stream>>>(fusedFR, el, er, b1, row_ptr,
                                               edge_src, outC, nullptr, N);
  mfma_gemm64<<<gD, 256, 0, stream>>>(outC, DWt1, Db1, denseD, N, 128, 512);
  gemm128el<false><<<gF, 256, 0, stream>>>(denseD, FW2, ALR + 2048, fusedFR,
                                           el, er, N, 1024, 128, nullptr, nullptr, 0);
  // ---- 11: layer 2 agg fused with graph pooling (slot partials)
  gat_agg_kernel<true><<<N, 256, 0, stream>>>(fusedFR, el, er, b2, row_ptr,
                                              edge_src, nullptr, partials, N);
  // ---- 12: final 64-slot max -> d_out
  pool_finish<<<1, 128, 0, stream>>>(partials, (float*)d_out);
}